// Round 8
// baseline (280.575 us; speedup 1.0000x reference)
//
#include <hip/hip_runtime.h>

#define KS 11
#define PAD 5
#define TDIM 32
#define HROWS 42          // TDIM + 2*PAD H-filtered rows
#define HPITCH 33         // odd pitch: V-pass reads conflict-free, H-writes ~2-way max
#define NTHREADS 512

typedef float v2f __attribute__((ext_vector_type(2)));

// Gaussian(sigma=1.5, 11 taps), normalized; 0 outside [0,10]
__device__ __forceinline__ constexpr float Wj(int j) {
    return (j < 0 || j > 10) ? 0.f :
           (j == 0 || j == 10) ? 0.00102838f :
           (j == 1 || j == 9)  ? 0.00759878f :
           (j == 2 || j == 8)  ? 0.03600077f :
           (j == 3 || j == 7)  ? 0.10936069f :
           (j == 4 || j == 6)  ? 0.21300553f : 0.26601172f;
}

// One block = one 32x32 output tile of one (b,c) image at this level.
// Moments filtered: 0:s=x1+x2, 1:d=x1-x2, 2:s^2, 3:d^2.
__global__ __launch_bounds__(NTHREADS, 8) void ssim_pool_kernel(
    const float* __restrict__ x1, const float* __restrict__ x2,
    float* __restrict__ p1, float* __restrict__ p2,
    float* __restrict__ accCS, float* __restrict__ accSSIM,
    int H, int W, int tilesX) {

    __shared__ __align__(16) float hbt[4 * HROWS * HPITCH];  // 22176 B
    __shared__ float red[16];

    const int t = threadIdx.x;
    const int tilesPerImg = tilesX * tilesX;
    const int img = blockIdx.x / tilesPerImg;
    const int rem = blockIdx.x % tilesPerImg;
    const int tyv = rem / tilesX;
    const int txv = rem % tilesX;
    const int b = img / 3;
    const int gy0 = tyv * TDIM;
    const int gx0 = txv * TDIM;

    const float* __restrict__ i1 = x1 + (size_t)img * H * W;
    const float* __restrict__ i2 = x2 + (size_t)img * H * W;

    // ---- fused 2x2 avg-pool for the next level (raw global reads, interior) ----
    if (p1 != nullptr && t < 256) {
        int py = t >> 4, px = t & 15;  // 16x16 pooled outputs per tile
        int rr = gy0 + 2 * py;
        int cc = gx0 + 2 * px;
        float2 a1 = *(const float2*)&i1[(size_t)rr * W + cc];
        float2 b1 = *(const float2*)&i1[(size_t)(rr + 1) * W + cc];
        float2 a2 = *(const float2*)&i2[(size_t)rr * W + cc];
        float2 b2 = *(const float2*)&i2[(size_t)(rr + 1) * W + cc];
        float v1 = 0.25f * (a1.x + a1.y + b1.x + b1.y);
        float v2 = 0.25f * (a2.x + a2.y + b2.x + b2.y);
        int Wp = W >> 1, Hp = H >> 1;
        size_t off = (size_t)img * Hp * Wp + (size_t)((gy0 >> 1) + py) * Wp + ((gx0 >> 1) + px);
        p1[off] = v1;
        p2[off] = v2;
    }

    // ---- H-pass: 8 colgroups x 42 rows = 336 tasks, one per thread ----
    if (t < 8 * HROWS) {
        int cg = t & 7;
        int r = t >> 3;
        int gy = gy0 + r - PAD;
        int gxlo = gx0 + (cg << 2) - 8;   // 16B-aligned when in-bounds

        float L1v[20], L2v[20];
#pragma unroll
        for (int e = 0; e < 20; ++e) { L1v[e] = 0.f; L2v[e] = 0.f; }

        if (gy >= 0 && gy < H) {
            const float* __restrict__ r1 = i1 + (size_t)gy * W;
            const float* __restrict__ r2 = i2 + (size_t)gy * W;
            if (gxlo >= 0 && gxlo + 20 <= W) {
#pragma unroll
                for (int q = 0; q < 5; ++q) {
                    *(float4*)&L1v[4 * q] = *(const float4*)&r1[gxlo + 4 * q];
                    *(float4*)&L2v[4 * q] = *(const float4*)&r2[gxlo + 4 * q];
                }
            } else {
#pragma unroll
                for (int e = 0; e < 20; ++e) {
                    int col = gxlo + e;
                    bool ok = (col >= 0) & (col < W);
                    L1v[e] = ok ? r1[ok ? col : 0] : 0.f;
                    L2v[e] = ok ? r2[ok ? col : 0] : 0.f;
                }
            }
        }

        // accA = outputs (k=0,1), accB = outputs (k=2,3) packed; 4 moments
        v2f accA[4], accB[4];
#pragma unroll
        for (int m = 0; m < 4; ++m) { accA[m] = (v2f){0.f, 0.f}; accB[m] = (v2f){0.f, 0.f}; }

        // window position i (0..13) = loaded element i+3; out[k] uses W(i-k)
#pragma unroll
        for (int i = 0; i < 14; ++i) {
            float v1 = L1v[i + 3], v2 = L2v[i + 3];
            float s = v1 + v2, d = v1 - v2;
            v2f sd = {s, d};
            v2f q = sd * sd;
            const v2f wA = {Wj(i), Wj(i - 1)};
            const v2f wB = {Wj(i - 2), Wj(i - 3)};
            v2f sb = {s, s}, db = {d, d};
            v2f qs = {q.x, q.x}, qd = {q.y, q.y};
            accA[0] = __builtin_elementwise_fma(wA, sb, accA[0]);
            accB[0] = __builtin_elementwise_fma(wB, sb, accB[0]);
            accA[1] = __builtin_elementwise_fma(wA, db, accA[1]);
            accB[1] = __builtin_elementwise_fma(wB, db, accB[1]);
            accA[2] = __builtin_elementwise_fma(wA, qs, accA[2]);
            accB[2] = __builtin_elementwise_fma(wB, qs, accB[2]);
            accA[3] = __builtin_elementwise_fma(wA, qd, accA[3]);
            accB[3] = __builtin_elementwise_fma(wB, qd, accB[3]);
        }
        int c0 = cg << 2;
#pragma unroll
        for (int m = 0; m < 4; ++m) {
            float* hb = &hbt[(m * HROWS + r) * HPITCH + c0];
            hb[0] = accA[m].x;
            hb[1] = accA[m].y;
            hb[2] = accB[m].x;
            hb[3] = accB[m].y;
        }
    }
    __syncthreads();

    // ---- V-pass: thread = (col, 2 rows); packed taps; conflict-free LDS reads ----
    const float C1 = 0.0001f;
    const float C2 = 0.0009f;
    float ssim_s = 0.f, cs_s = 0.f;
    {
        int c = t & 31;
        int r0 = (t >> 5) << 1;   // rows r0, r0+1

        v2f av[4];
#pragma unroll
        for (int m = 0; m < 4; ++m) av[m] = (v2f){0.f, 0.f};
#pragma unroll
        for (int m = 0; m < 4; ++m) {
#pragma unroll
            for (int i = 0; i < 12; ++i) {
                float w = hbt[(m * HROWS + r0 + i) * HPITCH + c];
                const v2f wp = {Wj(i), Wj(i - 1)};
                av[m] = __builtin_elementwise_fma(wp, (v2f){w, w}, av[m]);
            }
        }
#pragma unroll
        for (int k = 0; k < 2; ++k) {
            float Sm = (k == 0) ? av[0].x : av[0].y;
            float Dm = (k == 0) ? av[1].x : av[1].y;
            float SSm = (k == 0) ? av[2].x : av[2].y;
            float DDm = (k == 0) ? av[3].x : av[3].y;
            float Sm2 = Sm * Sm, Dm2 = Dm * Dm;
            float num_cs = 0.5f * (SSm - DDm - Sm2 + Dm2) + C2;   // 2*sigma12 + C2
            float den_cs = 0.5f * (SSm + DDm - Sm2 - Dm2) + C2;   // sigma1+sigma2 + C2
            float num_ss = 0.5f * (Sm2 - Dm2) + C1;               // 2*mu12 + C1
            float den_ss = 0.5f * (Sm2 + Dm2) + C1;               // mu1^2+mu2^2 + C1
            float cs = num_cs / den_cs;
            float ss = num_ss * cs / den_ss;
            cs_s += cs;
            ssim_s += ss;
        }
    }

    // ---- block reduction -> atomicAdd per (level, b) ----
#pragma unroll
    for (int o = 32; o > 0; o >>= 1) {
        ssim_s += __shfl_down(ssim_s, o);
        cs_s += __shfl_down(cs_s, o);
    }
    int wid = t >> 6, lane = t & 63;
    if (lane == 0) {
        red[wid] = ssim_s;
        red[8 + wid] = cs_s;
    }
    __syncthreads();
    if (t == 0) {
        float a = 0.f, c = 0.f;
#pragma unroll
        for (int k = 0; k < 8; ++k) { a += red[k]; c += red[8 + k]; }
        atomicAdd(&accSSIM[b], a);
        atomicAdd(&accCS[b], c);
    }
}

// acc layout: cs sums at acc[l*16+b], ssim sums at acc[80 + l*16+b]
__global__ void finalize_kernel(const float* __restrict__ acc, float* __restrict__ out) {
    __shared__ float vals[16];
    int t = threadIdx.x;
    if (t < 16) {
        const float w[5] = {0.0448f, 0.2856f, 0.3001f, 0.2363f, 0.1333f};
        float v = 1.f;
#pragma unroll
        for (int l = 0; l < 5; ++l) {
            int Hl = 512 >> l;
            float denom = 3.f * (float)Hl * (float)Hl;
            float m = (l < 4) ? acc[l * 16 + t] : acc[80 + l * 16 + t];
            m = m / denom;
            m = fmaxf(m, 0.f);
            v *= powf(m, w[l]);
        }
        vals[t] = v;
    }
    __syncthreads();
    if (t == 0) {
        float s = 0.f;
        for (int i = 0; i < 16; ++i) s += vals[i];
        out[0] = s / 16.f;
    }
}

extern "C" void kernel_launch(void* const* d_in, const int* in_sizes, int n_in,
                              void* d_out, int out_size, void* d_ws, size_t ws_size,
                              hipStream_t stream) {
    const float* img1 = (const float*)d_in[0];
    const float* img2 = (const float*)d_in[1];
    float* out = (float*)d_out;
    float* ws = (float*)d_ws;

    float* acc = ws;
    size_t off = 256;
    float* x1l[5];
    float* x2l[5];
    x1l[0] = (float*)img1;
    x2l[0] = (float*)img2;
    size_t lvlElems[5];
    for (int l = 0; l < 5; ++l) {
        int Hl = 512 >> l;
        lvlElems[l] = (size_t)48 * Hl * Hl;
    }
    for (int l = 1; l < 5; ++l) { x1l[l] = ws + off; off += lvlElems[l]; }
    for (int l = 1; l < 5; ++l) { x2l[l] = ws + off; off += lvlElems[l]; }

    hipMemsetAsync(acc, 0, 256 * sizeof(float), stream);

    for (int l = 0; l < 5; ++l) {
        int Hl = 512 >> l;
        int tiles = Hl / TDIM;
        int nblk = 48 * tiles * tiles;
        float* p1 = (l < 4) ? x1l[l + 1] : nullptr;
        float* p2 = (l < 4) ? x2l[l + 1] : nullptr;
        ssim_pool_kernel<<<nblk, NTHREADS, 0, stream>>>(
            x1l[l], x2l[l], p1, p2,
            acc + l * 16, acc + 80 + l * 16,
            Hl, Hl, tiles);
    }
    finalize_kernel<<<1, 64, 0, stream>>>(acc, out);
}

// Round 9
// 252.871 us; speedup vs baseline: 1.1096x; 1.1096x over previous
//
#include <hip/hip_runtime.h>

#define KS 11
#define PAD 5
#define TDIM 32
#define HROWS 42          // TDIM + 2*PAD H-filtered rows
#define HPITCH 33         // odd pitch: V-pass reads conflict-free, H-writes ~2-way max
#define NTHREADS 512

typedef float v2f __attribute__((ext_vector_type(2)));

// Gaussian(sigma=1.5, 11 taps), normalized; 0 outside [0,10]
__device__ __forceinline__ constexpr float Wj(int j) {
    return (j < 0 || j > 10) ? 0.f :
           (j == 0 || j == 10) ? 0.00102838f :
           (j == 1 || j == 9)  ? 0.00759878f :
           (j == 2 || j == 8)  ? 0.03600077f :
           (j == 3 || j == 7)  ? 0.10936069f :
           (j == 4 || j == 6)  ? 0.21300553f : 0.26601172f;
}

// One block = one 32x32 output tile of one (b,c) image at this level.
// Moments filtered: 0:s=x1+x2, 1:d=x1-x2, 2:s^2, 3:d^2.
// blockIdx is XCD-swizzled: each XCD owns a contiguous chunk of logical ids
// (= 6 whole images); within an image tiles are column-major so vertical
// halo rows are L2-shared on the same XCD.
__global__ __launch_bounds__(NTHREADS, 8) void ssim_pool_kernel(
    const float* __restrict__ x1, const float* __restrict__ x2,
    float* __restrict__ p1, float* __restrict__ p2,
    float* __restrict__ accCS, float* __restrict__ accSSIM,
    int H, int W, int tilesX) {

    __shared__ __align__(16) float hbt[4 * HROWS * HPITCH];  // 22176 B
    __shared__ float red[16];

    const int t = threadIdx.x;
    const int tilesPerImg = tilesX * tilesX;

    // ---- bijective XCD swizzle (grid always divisible by 8) ----
    const int cpx = gridDim.x >> 3;
    const int logical = (blockIdx.x & 7) * cpx + (blockIdx.x >> 3);

    const int img = logical / tilesPerImg;
    const int rem = logical % tilesPerImg;
    const int tyv = rem % tilesX;   // column-major: ty fastest
    const int txv = rem / tilesX;
    const int b = img / 3;
    const int gy0 = tyv * TDIM;
    const int gx0 = txv * TDIM;

    const float* __restrict__ i1 = x1 + (size_t)img * H * W;
    const float* __restrict__ i2 = x2 + (size_t)img * H * W;

    // ---- fused 2x2 avg-pool for the next level (raw global reads, interior) ----
    if (p1 != nullptr && t < 256) {
        int py = t >> 4, px = t & 15;  // 16x16 pooled outputs per tile
        int rr = gy0 + 2 * py;
        int cc = gx0 + 2 * px;
        float2 a1 = *(const float2*)&i1[(size_t)rr * W + cc];
        float2 b1 = *(const float2*)&i1[(size_t)(rr + 1) * W + cc];
        float2 a2 = *(const float2*)&i2[(size_t)rr * W + cc];
        float2 b2 = *(const float2*)&i2[(size_t)(rr + 1) * W + cc];
        float v1 = 0.25f * (a1.x + a1.y + b1.x + b1.y);
        float v2 = 0.25f * (a2.x + a2.y + b2.x + b2.y);
        int Wp = W >> 1, Hp = H >> 1;
        size_t off = (size_t)img * Hp * Wp + (size_t)((gy0 >> 1) + py) * Wp + ((gx0 >> 1) + px);
        p1[off] = v1;
        p2[off] = v2;
    }

    // ---- H-pass: 8 colgroups x 42 rows = 336 tasks, one per thread ----
    if (t < 8 * HROWS) {
        int cg = t & 7;
        int r = t >> 3;
        int gy = gy0 + r - PAD;
        int gxlo = gx0 + (cg << 2) - 8;   // 16B-aligned when in-bounds

        float L1v[20], L2v[20];
#pragma unroll
        for (int e = 0; e < 20; ++e) { L1v[e] = 0.f; L2v[e] = 0.f; }

        if (gy >= 0 && gy < H) {
            const float* __restrict__ r1 = i1 + (size_t)gy * W;
            const float* __restrict__ r2 = i2 + (size_t)gy * W;
            if (gxlo >= 0 && gxlo + 20 <= W) {
#pragma unroll
                for (int q = 0; q < 5; ++q) {
                    *(float4*)&L1v[4 * q] = *(const float4*)&r1[gxlo + 4 * q];
                    *(float4*)&L2v[4 * q] = *(const float4*)&r2[gxlo + 4 * q];
                }
            } else {
#pragma unroll
                for (int e = 0; e < 20; ++e) {
                    int col = gxlo + e;
                    bool ok = (col >= 0) & (col < W);
                    L1v[e] = ok ? r1[ok ? col : 0] : 0.f;
                    L2v[e] = ok ? r2[ok ? col : 0] : 0.f;
                }
            }
        }

        // accA = outputs (k=0,1), accB = outputs (k=2,3) packed; 4 moments
        v2f accA[4], accB[4];
#pragma unroll
        for (int m = 0; m < 4; ++m) { accA[m] = (v2f){0.f, 0.f}; accB[m] = (v2f){0.f, 0.f}; }

        // window position i (0..13) = loaded element i+3; out[k] uses W(i-k)
#pragma unroll
        for (int i = 0; i < 14; ++i) {
            float v1 = L1v[i + 3], v2 = L2v[i + 3];
            float s = v1 + v2, d = v1 - v2;
            v2f sd = {s, d};
            v2f q = sd * sd;
            const v2f wA = {Wj(i), Wj(i - 1)};
            const v2f wB = {Wj(i - 2), Wj(i - 3)};
            v2f sb = {s, s}, db = {d, d};
            v2f qs = {q.x, q.x}, qd = {q.y, q.y};
            accA[0] = __builtin_elementwise_fma(wA, sb, accA[0]);
            accB[0] = __builtin_elementwise_fma(wB, sb, accB[0]);
            accA[1] = __builtin_elementwise_fma(wA, db, accA[1]);
            accB[1] = __builtin_elementwise_fma(wB, db, accB[1]);
            accA[2] = __builtin_elementwise_fma(wA, qs, accA[2]);
            accB[2] = __builtin_elementwise_fma(wB, qs, accB[2]);
            accA[3] = __builtin_elementwise_fma(wA, qd, accA[3]);
            accB[3] = __builtin_elementwise_fma(wB, qd, accB[3]);
        }
        int c0 = cg << 2;
#pragma unroll
        for (int m = 0; m < 4; ++m) {
            float* hb = &hbt[(m * HROWS + r) * HPITCH + c0];
            hb[0] = accA[m].x;
            hb[1] = accA[m].y;
            hb[2] = accB[m].x;
            hb[3] = accB[m].y;
        }
    }
    __syncthreads();

    // ---- V-pass: thread = (col, 2 rows); packed taps; conflict-free LDS reads ----
    const float C1 = 0.0001f;
    const float C2 = 0.0009f;
    float ssim_s = 0.f, cs_s = 0.f;
    {
        int c = t & 31;
        int r0 = (t >> 5) << 1;   // rows r0, r0+1

        v2f av[4];
#pragma unroll
        for (int m = 0; m < 4; ++m) av[m] = (v2f){0.f, 0.f};
#pragma unroll
        for (int m = 0; m < 4; ++m) {
#pragma unroll
            for (int i = 0; i < 12; ++i) {
                float w = hbt[(m * HROWS + r0 + i) * HPITCH + c];
                const v2f wp = {Wj(i), Wj(i - 1)};
                av[m] = __builtin_elementwise_fma(wp, (v2f){w, w}, av[m]);
            }
        }
#pragma unroll
        for (int k = 0; k < 2; ++k) {
            float Sm = (k == 0) ? av[0].x : av[0].y;
            float Dm = (k == 0) ? av[1].x : av[1].y;
            float SSm = (k == 0) ? av[2].x : av[2].y;
            float DDm = (k == 0) ? av[3].x : av[3].y;
            float Sm2 = Sm * Sm, Dm2 = Dm * Dm;
            float num_cs = 0.5f * (SSm - DDm - Sm2 + Dm2) + C2;   // 2*sigma12 + C2
            float den_cs = 0.5f * (SSm + DDm - Sm2 - Dm2) + C2;   // sigma1+sigma2 + C2
            float num_ss = 0.5f * (Sm2 - Dm2) + C1;               // 2*mu12 + C1
            float den_ss = 0.5f * (Sm2 + Dm2) + C1;               // mu1^2+mu2^2 + C1
            float cs = num_cs / den_cs;
            float ss = num_ss * cs / den_ss;
            cs_s += cs;
            ssim_s += ss;
        }
    }

    // ---- block reduction -> atomicAdd per (level, b) ----
#pragma unroll
    for (int o = 32; o > 0; o >>= 1) {
        ssim_s += __shfl_down(ssim_s, o);
        cs_s += __shfl_down(cs_s, o);
    }
    int wid = t >> 6, lane = t & 63;
    if (lane == 0) {
        red[wid] = ssim_s;
        red[8 + wid] = cs_s;
    }
    __syncthreads();
    if (t == 0) {
        float a = 0.f, c = 0.f;
#pragma unroll
        for (int k = 0; k < 8; ++k) { a += red[k]; c += red[8 + k]; }
        atomicAdd(&accSSIM[b], a);
        atomicAdd(&accCS[b], c);
    }
}

// acc layout: cs sums at acc[l*16+b], ssim sums at acc[80 + l*16+b]
__global__ void finalize_kernel(const float* __restrict__ acc, float* __restrict__ out) {
    __shared__ float vals[16];
    int t = threadIdx.x;
    if (t < 16) {
        const float w[5] = {0.0448f, 0.2856f, 0.3001f, 0.2363f, 0.1333f};
        float v = 1.f;
#pragma unroll
        for (int l = 0; l < 5; ++l) {
            int Hl = 512 >> l;
            float denom = 3.f * (float)Hl * (float)Hl;
            float m = (l < 4) ? acc[l * 16 + t] : acc[80 + l * 16 + t];
            m = m / denom;
            m = fmaxf(m, 0.f);
            v *= powf(m, w[l]);
        }
        vals[t] = v;
    }
    __syncthreads();
    if (t == 0) {
        float s = 0.f;
        for (int i = 0; i < 16; ++i) s += vals[i];
        out[0] = s / 16.f;
    }
}

extern "C" void kernel_launch(void* const* d_in, const int* in_sizes, int n_in,
                              void* d_out, int out_size, void* d_ws, size_t ws_size,
                              hipStream_t stream) {
    const float* img1 = (const float*)d_in[0];
    const float* img2 = (const float*)d_in[1];
    float* out = (float*)d_out;
    float* ws = (float*)d_ws;

    float* acc = ws;
    size_t off = 256;
    float* x1l[5];
    float* x2l[5];
    x1l[0] = (float*)img1;
    x2l[0] = (float*)img2;
    size_t lvlElems[5];
    for (int l = 0; l < 5; ++l) {
        int Hl = 512 >> l;
        lvlElems[l] = (size_t)48 * Hl * Hl;
    }
    for (int l = 1; l < 5; ++l) { x1l[l] = ws + off; off += lvlElems[l]; }
    for (int l = 1; l < 5; ++l) { x2l[l] = ws + off; off += lvlElems[l]; }

    hipMemsetAsync(acc, 0, 256 * sizeof(float), stream);

    for (int l = 0; l < 5; ++l) {
        int Hl = 512 >> l;
        int tiles = Hl / TDIM;
        int nblk = 48 * tiles * tiles;
        float* p1 = (l < 4) ? x1l[l + 1] : nullptr;
        float* p2 = (l < 4) ? x2l[l + 1] : nullptr;
        ssim_pool_kernel<<<nblk, NTHREADS, 0, stream>>>(
            x1l[l], x2l[l], p1, p2,
            acc + l * 16, acc + 80 + l * 16,
            Hl, Hl, tiles);
    }
    finalize_kernel<<<1, 64, 0, stream>>>(acc, out);
}